// Round 8
// baseline (15719.458 us; speedup 1.0000x reference)
//
#include <hip/hip_runtime.h>
#include <hip/hip_bf16.h>
#include <math.h>

#define NBATCH 128
#define NATOM  80
#define SENC   80
#define SDEC   160
#define HGDIM  512
#define HIDDIM 256
#define NHEAD  8
#define DH_E   64
#define DH_D   32
#define ROWS_E (NBATCH*NATOM)   /* 10240 */
#define ROWS_D (NBATCH*SDEC)    /* 20480 */

// ---------------- workspace layout (float offsets) ----------------
#define OFF_REAL 0ull                      /* 10240                        */
#define OFF_FLAG 10240ull                  /* 1 int: mask dtype flag       */
#define OFF_H    16384ull                  /* 5242880  enc h / dec x       */
#define OFF_LN   (OFF_H  + 5242880ull)     /* 5242880  LN out              */
#define OFF_BIG  (OFF_LN + 5242880ull)     /* 20971520 qkv / ffn / a1      */
#define OFF_AO   (OFF_BIG+ 20971520ull)    /* 5242880  attn out            */
#define OFF_DB   (OFF_AO + 5242880ull)     /* 6553600  enc attn bias       */
#define OFF_REP  (OFF_DB + 6553600ull)     /* 2621440  rep / h_out         */
#define OFF_MOM  (OFF_REP+ 2621440ull)     /* 122880   moments (10240x12)  */
#define OFF_KL   (OFF_MOM+ 122880ull)      /* 64       kl partials         */
#define NEED_BYTES 184058112ull

// mask dtype probe, atomic-free. flag=1 -> bool bytes, 0 -> int32.
__global__ void k_maskmode(const unsigned char* __restrict__ m, int* __restrict__ flag){
  __shared__ int sh[256];
  int loc = 0;
  for(int i=threadIdx.x; i<ROWS_E; i+=256)
    if((i&3)!=0 && m[i]) loc = 1;
  sh[threadIdx.x] = loc;
  __syncthreads();
  if(threadIdx.x==0){
    int a=0;
    for(int j=0;j<256;j++) a |= sh[j];
    *flag = a;
  }
}

__global__ void k_real(const unsigned char* __restrict__ m, const int* __restrict__ flag,
                       float* __restrict__ real){
  int i = blockIdx.x*256 + threadIdx.x;
  if(i >= ROWS_E) return;
  int v = (*flag) ? (int)m[i] : ((const int*)m)[i];
  real[i] = v ? 0.f : 1.f;
}

__global__ void k_wsfail(float* __restrict__ out, float code){
  if(threadIdx.x==0) out[0] = code;
}

__global__ void k_embed(const float* __restrict__ atom, const float* __restrict__ W,
                        float* __restrict__ h){
  int idx = blockIdx.x*256 + threadIdx.x;           // row*512 + c
  if(idx >= ROWS_E*HGDIM) return;
  int row = idx >> 9, c = idx & 511;
  float s = 0.f;
  #pragma unroll
  for(int a=0;a<16;a++) s += atom[row*16+a] * W[a*HGDIM+c];
  h[idx] = s;
}

__global__ __launch_bounds__(256) void k_ln(const float* __restrict__ x,
    const float* __restrict__ g, const float* __restrict__ bta,
    float* __restrict__ y, int D){
  size_t row = blockIdx.x;
  const float* xr = x + row*D;
  float* yr = y + row*D;
  int t = threadIdx.x;
  float s=0.f, s2=0.f;
  for(int c=t;c<D;c+=256){ float v=xr[c]; s+=v; s2+=v*v; }
  #pragma unroll
  for(int o=32;o>0;o>>=1){ s += __shfl_xor(s,o); s2 += __shfl_xor(s2,o); }
  __shared__ float ra[4], rb[4];
  int w = t>>6;
  if((t&63)==0){ ra[w]=s; rb[w]=s2; }
  __syncthreads();
  float ts  = ra[0]+ra[1]+ra[2]+ra[3];
  float ts2 = rb[0]+rb[1]+rb[2]+rb[3];
  float mean = ts / D;
  float var  = fmaxf(ts2 / D - mean*mean, 0.f);
  float inv  = rsqrtf(var + 1e-5f);
  for(int c=t;c<D;c+=256){
    float v = (xr[c]-mean)*inv;
    yr[c] = v*g[c] + bta[c];
  }
}

// rbf attention bias for one encoder block: db[b][h][q][k]
__global__ void k_db(const float* __restrict__ coord, const float* __restrict__ real,
                     const float* __restrict__ rbfw, float* __restrict__ db){
  int idx = blockIdx.x*256 + threadIdx.x;   // b*6400 + q*80 + k
  if(idx >= NBATCH*SENC*SENC) return;
  int b = idx/(SENC*SENC), r = idx%(SENC*SENC), q = r/SENC, k = r%SENC;
  float out[NHEAD];
  bool masked = (real[b*NATOM+k]==0.f) || (k==q);
  if(masked){
    #pragma unroll
    for(int h=0;h<NHEAD;h++) out[h] = -1e9f;
  } else {
    float dx = coord[(b*NATOM+q)*3+0] - coord[(b*NATOM+k)*3+0];
    float dy = coord[(b*NATOM+q)*3+1] - coord[(b*NATOM+k)*3+1];
    float dz = coord[(b*NATOM+q)*3+2] - coord[(b*NATOM+k)*3+2];
    float d  = sqrtf(dx*dx+dy*dy+dz*dz + 1e-12f);
    #pragma unroll
    for(int h=0;h<NHEAD;h++) out[h]=0.f;
    for(int rr=0;rr<16;rr++){
      float cen = (10.f/15.f)*rr;
      float e = expf(-2.f*(d-cen)*(d-cen));
      #pragma unroll
      for(int h=0;h<NHEAD;h++) out[h] += e * rbfw[rr*NHEAD+h];
    }
  }
  #pragma unroll
  for(int h=0;h<NHEAD;h++)
    db[(((size_t)b*NHEAD+h)*SENC + q)*SENC + k] = out[h];
}

// fused attention: one wave per (b,h,q). qkv rows: (b*S+s) x (3*D), q|k|v blocks.
__global__ __launch_bounds__(256) void k_attn(
    const float* __restrict__ qkv, const float* __restrict__ db,
    const float* __restrict__ real, float* __restrict__ o,
    int S, int H, int dh, float scale, int mode)
{
  __shared__ float qs[4][64];
  __shared__ float sc[4][160];
  int w = threadIdx.x >> 6, ln = threadIdx.x & 63;
  int fl = blockIdx.x*4 + w;
  int q = fl % S; int bh = fl / S; int h = bh % H; int b = bh / H;
  int D = H*dh, D3 = 3*D;
  const float* base = qkv + (size_t)b*S*D3;
  if(ln < dh) qs[w][ln] = base[(size_t)q*D3 + h*dh + ln];
  __syncthreads();
  float m = -1e30f;
  for(int k0=0;k0<S;k0+=64){
    int k = k0+ln;
    float s = -1e30f;
    if(k<S){
      const float* krow = base + (size_t)k*D3 + D + h*dh;
      float dot=0.f;
      for(int d=0;d<dh;d++) dot += qs[w][d]*krow[d];
      s = dot*scale;
      if(mode==0){
        s += db[(((size_t)b*H + h)*S + q)*S + k];
      } else {
        int kk = (k<NATOM)? k : k-NATOM;
        if(real[b*NATOM+kk]==0.f) s -= 1e9f;
      }
      sc[w][k]=s;
    }
    m = fmaxf(m,s);
  }
  #pragma unroll
  for(int off=32;off>0;off>>=1) m = fmaxf(m, __shfl_xor(m,off));
  float sum=0.f;
  for(int k0=0;k0<S;k0+=64){
    int k=k0+ln;
    if(k<S){ float e=expf(sc[w][k]-m); sc[w][k]=e; sum+=e; }
  }
  #pragma unroll
  for(int off=32;off>0;off>>=1) sum += __shfl_xor(sum,off);
  float inv = 1.f/sum;
  __syncthreads();
  if(ln<dh){
    const float* vcol = base + 2*D + h*dh + ln;
    float acc=0.f;
    for(int k=0;k<S;k++) acc += sc[w][k]*vcol[(size_t)k*D3];
    o[((size_t)(b*S+q))*D + h*dh + ln] = acc*inv;
  }
}

// fp32 tiled GEMM: C[M,N] = epi(A[M,K] @ W[K,N]); M%64==0, N%64==0, K%16==0
__global__ __launch_bounds__(256) void k_gemm64(
    const float* __restrict__ A, const float* __restrict__ W, const float* __restrict__ bias,
    const float* __restrict__ resid, const float* __restrict__ rowscale,
    float* __restrict__ C,
    int M, int K, int Nw, int act)
{
  __shared__ float As[16][65];
  __shared__ float Ws[16][64];
  int tid = threadIdx.x;
  int tx = tid & 15, ty = tid >> 4;
  int row0 = blockIdx.y*64, col0 = blockIdx.x*64;
  float acc[4][4] = {};
  for(int k0=0;k0<K;k0+=16){
    {
      int k = tid & 15, mbase = tid >> 4;
      #pragma unroll
      for(int l=0;l<4;l++){
        int mm = mbase + l*16;
        As[k][mm] = A[(size_t)(row0+mm)*K + k0 + k];
      }
    }
    {
      int n = tid & 63, kb = tid >> 6;
      #pragma unroll
      for(int l=0;l<4;l++){
        int kk = kb + l*4;
        Ws[kk][n] = W[(size_t)(k0+kk)*Nw + col0 + n];
      }
    }
    __syncthreads();
    #pragma unroll
    for(int kk=0;kk<16;kk++){
      float a[4], bb[4];
      #pragma unroll
      for(int i=0;i<4;i++) a[i]=As[kk][ty+16*i];
      #pragma unroll
      for(int j=0;j<4;j++) bb[j]=Ws[kk][tx+16*j];
      #pragma unroll
      for(int i=0;i<4;i++)
        #pragma unroll
        for(int j=0;j<4;j++) acc[i][j] += a[i]*bb[j];
    }
    __syncthreads();
  }
  #pragma unroll
  for(int i=0;i<4;i++){
    int row = row0 + ty + 16*i;
    float rs = rowscale ? rowscale[row] : 1.f;
    #pragma unroll
    for(int j=0;j<4;j++){
      int col = col0 + tx + 16*j;
      float c = acc[i][j];
      if(bias)  c += bias[col];
      if(resid) c += resid[(size_t)row*Nw + col];
      if(act==1) c = c/(1.f+expf(-c));   // silu
      c *= rs;
      C[(size_t)row*Nw + col] = c;
    }
  }
}

// thread-per-output GEMM for tiny N
__global__ void k_gemm_small(const float* __restrict__ A, const float* __restrict__ W,
    const float* __restrict__ bias, float* __restrict__ C,
    int M, int K, int Nw, int act){
  int idx = blockIdx.x*256 + threadIdx.x;
  if(idx >= M*Nw) return;
  int row = idx / Nw, col = idx % Nw;
  float s = bias ? bias[col] : 0.f;
  const float* a = A + (size_t)row*K;
  for(int k=0;k<K;k++) s += a[k]*W[(size_t)k*Nw+col];
  if(act==1) s = s/(1.f+expf(-s));
  C[idx] = s;
}

__global__ __launch_bounds__(256) void k_kl(const float* __restrict__ mom,
    const float* __restrict__ real, float* __restrict__ part){
  int i = blockIdx.x*256 + threadIdx.x;
  float s = 0.f;
  if(i < ROWS_E){
    const float* m = mom + (size_t)i*12;
    float acc = 0.f;
    #pragma unroll
    for(int d=0;d<6;d++){ float mu=m[d], lv=m[6+d]; acc += 1.f + lv - mu*mu - expf(lv); }
    s = acc * real[i];
  }
  #pragma unroll
  for(int o=32;o>0;o>>=1) s += __shfl_xor(s,o);
  __shared__ float r[4];
  if((threadIdx.x&63)==0) r[threadIdx.x>>6]=s;
  __syncthreads();
  if(threadIdx.x==0) part[blockIdx.x] = r[0]+r[1]+r[2]+r[3];
}

__global__ void k_klfin(const float* __restrict__ part, float* __restrict__ o){
  float s=0.f;
  for(int i=0;i<40;i++) s += part[i];
  *o = -0.5f * (s/(float)ROWS_E) * 1e-6f;
}

__global__ __launch_bounds__(256) void k_build_x(
  const float* __restrict__ coord_t, const float* __restrict__ atomics_t, const float* __restrict__ tin,
  const float* __restrict__ qout_w, const float* __restrict__ qout_b, const float* __restrict__ cond,
  const float* __restrict__ lin_w, const float* __restrict__ atom_emb,
  const float* __restrict__ mom, const float* __restrict__ real, float* __restrict__ x)
{
  int idx = blockIdx.x*256 + threadIdx.x;
  if(idx >= NBATCH*SDEC*HIDDIM) return;
  int c = idx & 255; int rowg = idx >> 8; int s = rowg % SDEC; int b = rowg / SDEC;
  int n = (s<NATOM)? s : s-NATOM;
  int j = c >> 1;
  float div = expf(-(float)(2*j) * (9.210340371976184f/256.f));   // ln(10000)/HID
  float ang = (float)n * div;
  float pe = (c & 1) ? cosf(ang) : sinf(ang);
  float rl = real[b*NATOM + n];
  float v;
  if(s < NATOM){
    int rown = b*NATOM + n;
    float cl = 0.f;
    #pragma unroll
    for(int a=0;a<3;a++) cl += coord_t[rown*3+a] * lin_w[a*HIDDIM+c];
    int bi=0; float bv = atomics_t[rown*16];
    for(int a=1;a<16;a++){ float vv=atomics_t[rown*16+a]; if(vv>bv){bv=vv; bi=a;} }
    float ae = atom_emb[bi*HIDDIM+c];
    float tb = tin[b];
    float tf;
    if(c < 128){
      float fr = expf(-(float)c * (5.298317366548036f/128.f));    // ln(200)/128
      tf = sinf(tb*200.f*fr);
    } else {
      float fr = expf(-(float)(c-128) * (5.298317366548036f/128.f));
      tf = cosf(tb*200.f*fr);
    }
    v = (cl + ae + pe + tf)*rl + cond[c];
  } else {
    int rown = b*NATOM + n;
    const float* mp = mom + (size_t)rown*12;
    float s2 = qout_b[c];
    #pragma unroll
    for(int d=0;d<6;d++) s2 += mp[d]*qout_w[d*HIDDIM+c];
    v = (s2 + pe)*rl + cond[HIDDIM+c];
  }
  x[idx] = v;
}

__global__ void k_hout(const float* __restrict__ x, const float* __restrict__ real,
                       float* __restrict__ h_out){
  int idx = blockIdx.x*256 + threadIdx.x;
  if(idx >= ROWS_E*HIDDIM) return;
  int c = idx & 255, row = idx >> 8;
  int n = row % NATOM, b = row / NATOM;
  h_out[idx] = x[((size_t)(b*SDEC+n))*HIDDIM + c] * real[row];
}

// ---------------- launch ----------------
extern "C" void kernel_launch(void* const* d_in, const int* in_sizes, int n_in,
                              void* d_out, int out_size, void* d_ws, size_t ws_size,
                              hipStream_t stream){
  (void)in_sizes; (void)n_in; (void)out_size;
  const float* coord_ori   = (const float*)d_in[0];
  const float* atomics_ori = (const float*)d_in[1];
  const unsigned char* pmask = (const unsigned char*)d_in[2];
  const float* coord_t     = (const float*)d_in[3];
  const float* atomics_t   = (const float*)d_in[4];
  const float* t_in        = (const float*)d_in[5];
  const float* enc_embed_w = (const float*)d_in[6];
  const float* rbf_w       = (const float*)d_in[7];
  const float* e_qkv_w=(const float*)d_in[8];  const float* e_qkv_b=(const float*)d_in[9];
  const float* e_out_w=(const float*)d_in[10]; const float* e_out_b=(const float*)d_in[11];
  const float* e_ff1_w=(const float*)d_in[12]; const float* e_ff1_b=(const float*)d_in[13];
  const float* e_ff2_w=(const float*)d_in[14]; const float* e_ff2_b=(const float*)d_in[15];
  const float* e_ln1_g=(const float*)d_in[16]; const float* e_ln1_b=(const float*)d_in[17];
  const float* e_ln2_g=(const float*)d_in[18]; const float* e_ln2_b=(const float*)d_in[19];
  const float* enc_proj_w=(const float*)d_in[20];
  const float* quant_w=(const float*)d_in[21]; const float* quant_b=(const float*)d_in[22];
  const float* qout_w=(const float*)d_in[23];  const float* qout_b=(const float*)d_in[24];
  const float* cond_embed=(const float*)d_in[25];
  const float* lin_embed_w=(const float*)d_in[26];
  const float* atom_embed=(const float*)d_in[27];
  const float* d_qkv_w=(const float*)d_in[28]; const float* d_qkv_b=(const float*)d_in[29];
  const float* d_ow   =(const float*)d_in[30]; const float* d_ob   =(const float*)d_in[31];
  const float* d_ff1_w=(const float*)d_in[32]; const float* d_ff1_b=(const float*)d_in[33];
  const float* d_ff2_w=(const float*)d_in[34]; const float* d_ff2_b=(const float*)d_in[35];
  const float* d_ln1_g=(const float*)d_in[36]; const float* d_ln1_b=(const float*)d_in[37];
  const float* d_ln2_g=(const float*)d_in[38]; const float* d_ln2_b=(const float*)d_in[39];
  const float* oc_ln_g=(const float*)d_in[40]; const float* oc_ln_b=(const float*)d_in[41];
  const float* oc_w   =(const float*)d_in[42];
  const float* oa1_w  =(const float*)d_in[43]; const float* oa1_b=(const float*)d_in[44];
  const float* oa2_w  =(const float*)d_in[45]; const float* oa2_b=(const float*)d_in[46];

  float* ws   = (float*)d_ws;
  float* real = ws + OFF_REAL;
  int*   flag = (int*)(ws + OFF_FLAG);
  float* h    = ws + OFF_H;      // enc h, then dec x
  float* lnb  = ws + OFF_LN;
  float* big  = ws + OFF_BIG;    // qkv / ffn / a1
  float* ao   = ws + OFF_AO;
  float* db   = ws + OFF_DB;
  float* rep  = ws + OFF_REP;    // rep, then h_out
  float* mom  = ws + OFF_MOM;
  float* klp  = ws + OFF_KL;
  float* out  = (float*)d_out;   // fp32 outputs: coords | atom_logits | kl

  if(ws_size < NEED_BYTES){
    // encode workspace shortfall so it is visible in the absmax error
    k_wsfail<<<1,64,0,stream>>>(out, 1.0e6f + (float)(ws_size>>20));
    return;
  }

  k_maskmode<<<1,256,0,stream>>>(pmask, flag);
  k_real <<<40,   256, 0, stream>>>(pmask, flag, real);
  k_embed<<<20480,256, 0, stream>>>(atomics_ori, enc_embed_w, h);

  // ===== encoder =====
  for(int i=0;i<4;i++){
    k_ln<<<ROWS_E,256,0,stream>>>(h, e_ln1_g+i*HGDIM, e_ln1_b+i*HGDIM, lnb, HGDIM);
    k_gemm64<<<dim3(24,160),256,0,stream>>>(lnb, e_qkv_w+(size_t)i*HGDIM*3*HGDIM,
        e_qkv_b+i*3*HGDIM, nullptr, nullptr, big, ROWS_E, HGDIM, 3*HGDIM, 0);
    k_db<<<3200,256,0,stream>>>(coord_ori, real, rbf_w + i*16*NHEAD, db);
    k_attn<<<20480,256,0,stream>>>(big, db, real, ao, SENC, NHEAD, DH_E, 0.125f, 0);
    k_gemm64<<<dim3(8,160),256,0,stream>>>(ao, e_out_w+(size_t)i*HGDIM*HGDIM,
        e_out_b+i*HGDIM, h, nullptr, h, ROWS_E, HGDIM, HGDIM, 0);
    k_ln<<<ROWS_E,256,0,stream>>>(h, e_ln2_g+i*HGDIM, e_ln2_b+i*HGDIM, lnb, HGDIM);
    k_gemm64<<<dim3(32,160),256,0,stream>>>(lnb, e_ff1_w+(size_t)i*HGDIM*4*HGDIM,
        e_ff1_b+i*4*HGDIM, nullptr, nullptr, big, ROWS_E, HGDIM, 4*HGDIM, 1);
    k_gemm64<<<dim3(8,160),256,0,stream>>>(big, e_ff2_w+(size_t)i*4*HGDIM*HGDIM,
        e_ff2_b+i*HGDIM, h, nullptr, h, ROWS_E, 4*HGDIM, HGDIM, 0);
  }

  // rep = (h*real) @ enc_proj  (rowscale epilogue)
  k_gemm64<<<dim3(4,160),256,0,stream>>>(h, enc_proj_w, nullptr, nullptr, real,
      rep, ROWS_E, HGDIM, HIDDIM, 0);
  k_gemm_small<<<480,256,0,stream>>>(rep, quant_w, quant_b, mom, ROWS_E, HIDDIM, 12, 0);
  k_kl   <<<40,256,0,stream>>>(mom, real, klp);
  k_klfin<<<1,1,0,stream>>>(klp, out + 194560);

  // ===== decoder input =====
  k_build_x<<<20480,256,0,stream>>>(coord_t, atomics_t, t_in, qout_w, qout_b,
      cond_embed, lin_embed_w, atom_embed, mom, real, h);

  // ===== decoder =====
  for(int i=0;i<8;i++){
    k_ln<<<ROWS_D,256,0,stream>>>(h, d_ln1_g+i*HIDDIM, d_ln1_b+i*HIDDIM, lnb, HIDDIM);
    k_gemm64<<<dim3(12,320),256,0,stream>>>(lnb, d_qkv_w+(size_t)i*HIDDIM*3*HIDDIM,
        d_qkv_b+i*3*HIDDIM, nullptr, nullptr, big, ROWS_D, HIDDIM, 3*HIDDIM, 0);
    k_attn<<<40960,256,0,stream>>>(big, nullptr, real, ao, SDEC, NHEAD, DH_D,
        0.17677669529663689f, 1);
    k_gemm64<<<dim3(4,320),256,0,stream>>>(ao, d_ow+(size_t)i*HIDDIM*HIDDIM,
        d_ob+i*HIDDIM, h, nullptr, h, ROWS_D, HIDDIM, HIDDIM, 0);
    k_ln<<<ROWS_D,256,0,stream>>>(h, d_ln2_g+i*HIDDIM, d_ln2_b+i*HIDDIM, lnb, HIDDIM);
    k_gemm64<<<dim3(16,320),256,0,stream>>>(lnb, d_ff1_w+(size_t)i*HIDDIM*4*HIDDIM,
        d_ff1_b+i*4*HIDDIM, nullptr, nullptr, big, ROWS_D, HIDDIM, 4*HIDDIM, 1);
    k_gemm64<<<dim3(4,320),256,0,stream>>>(big, d_ff2_w+(size_t)i*4*HIDDIM*HIDDIM,
        d_ff2_b+i*HIDDIM, h, nullptr, h, ROWS_D, 4*HIDDIM, HIDDIM, 0);
  }

  // ===== heads =====
  k_hout<<<10240,256,0,stream>>>(h, real, rep);                      // rep := h_out
  k_ln<<<ROWS_E,256,0,stream>>>(rep, oc_ln_g, oc_ln_b, lnb, HIDDIM);
  k_gemm_small<<<120,256,0,stream>>>(lnb, oc_w, nullptr, out, ROWS_E, HIDDIM, 3, 0);
  k_gemm64<<<dim3(4,160),256,0,stream>>>(rep, oa1_w, oa1_b, nullptr, nullptr,
      big, ROWS_E, HIDDIM, HIDDIM, 1);
  k_gemm_small<<<640,256,0,stream>>>(big, oa2_w, oa2_b, out + 30720,
      ROWS_E, HIDDIM, 16, 0);
}

// Round 9
// 9725.476 us; speedup vs baseline: 1.6163x; 1.6163x over previous
//
#include <hip/hip_runtime.h>
#include <hip/hip_bf16.h>
#include <math.h>

#define NBATCH 128
#define NATOM  80
#define SENC   80
#define SDEC   160
#define HGDIM  512
#define HIDDIM 256
#define NHEAD  8
#define DH_E   64
#define DH_D   32
#define ROWS_E (NBATCH*NATOM)   /* 10240 */
#define ROWS_D (NBATCH*SDEC)    /* 20480 */

// ---------------- workspace layout (float offsets) ----------------
#define OFF_REAL 0ull
#define OFF_FLAG 10240ull
#define OFF_H    16384ull
#define OFF_LN   (OFF_H  + 5242880ull)
#define OFF_BIG  (OFF_LN + 5242880ull)
#define OFF_AO   (OFF_BIG+ 20971520ull)
#define OFF_DB   (OFF_AO + 5242880ull)
#define OFF_REP  (OFF_DB + 6553600ull)
#define OFF_MOM  (OFF_REP+ 2621440ull)
#define OFF_KL   (OFF_MOM+ 122880ull)
#define NEED_BYTES 184058112ull

// mask dtype probe, atomic-free. flag=1 -> bool bytes, 0 -> int32.
__global__ void k_maskmode(const unsigned char* __restrict__ m, int* __restrict__ flag){
  __shared__ int sh[256];
  int loc = 0;
  for(int i=threadIdx.x; i<ROWS_E; i+=256)
    if((i&3)!=0 && m[i]) loc = 1;
  sh[threadIdx.x] = loc;
  __syncthreads();
  if(threadIdx.x==0){
    int a=0;
    for(int j=0;j<256;j++) a |= sh[j];
    *flag = a;
  }
}

__global__ void k_real(const unsigned char* __restrict__ m, const int* __restrict__ flag,
                       float* __restrict__ real){
  int i = blockIdx.x*256 + threadIdx.x;
  if(i >= ROWS_E) return;
  int v = (*flag) ? (int)m[i] : ((const int*)m)[i];
  real[i] = v ? 0.f : 1.f;
}

__global__ void k_wsfail(float* __restrict__ out, float code){
  if(threadIdx.x==0) out[0] = code;
}

__global__ void k_embed(const float* __restrict__ atom, const float* __restrict__ W,
                        float* __restrict__ h){
  int idx = blockIdx.x*256 + threadIdx.x;
  if(idx >= ROWS_E*HGDIM) return;
  int row = idx >> 9, c = idx & 511;
  float s = 0.f;
  #pragma unroll
  for(int a=0;a<16;a++) s += atom[row*16+a] * W[a*HGDIM+c];
  h[idx] = s;
}

__global__ __launch_bounds__(256) void k_ln(const float* __restrict__ x,
    const float* __restrict__ g, const float* __restrict__ bta,
    float* __restrict__ y, int D){
  size_t row = blockIdx.x;
  const float* xr = x + row*D;
  float* yr = y + row*D;
  int t = threadIdx.x;
  float s=0.f, s2=0.f;
  for(int c=t;c<D;c+=256){ float v=xr[c]; s+=v; s2+=v*v; }
  #pragma unroll
  for(int o=32;o>0;o>>=1){ s += __shfl_xor(s,o); s2 += __shfl_xor(s2,o); }
  __shared__ float ra[4], rb[4];
  int w = t>>6;
  if((t&63)==0){ ra[w]=s; rb[w]=s2; }
  __syncthreads();
  float ts  = ra[0]+ra[1]+ra[2]+ra[3];
  float ts2 = rb[0]+rb[1]+rb[2]+rb[3];
  float mean = ts / D;
  float var  = fmaxf(ts2 / D - mean*mean, 0.f);
  float inv  = rsqrtf(var + 1e-5f);
  for(int c=t;c<D;c+=256){
    float v = (xr[c]-mean)*inv;
    yr[c] = v*g[c] + bta[c];
  }
}

// rbf attention bias for one encoder block: db[b][h][q][k]
__global__ void k_db(const float* __restrict__ coord, const float* __restrict__ real,
                     const float* __restrict__ rbfw, float* __restrict__ db){
  int idx = blockIdx.x*256 + threadIdx.x;
  if(idx >= NBATCH*SENC*SENC) return;
  int b = idx/(SENC*SENC), r = idx%(SENC*SENC), q = r/SENC, k = r%SENC;
  float out[NHEAD];
  bool masked = (real[b*NATOM+k]==0.f) || (k==q);
  if(masked){
    #pragma unroll
    for(int h=0;h<NHEAD;h++) out[h] = -1e9f;
  } else {
    float dx = coord[(b*NATOM+q)*3+0] - coord[(b*NATOM+k)*3+0];
    float dy = coord[(b*NATOM+q)*3+1] - coord[(b*NATOM+k)*3+1];
    float dz = coord[(b*NATOM+q)*3+2] - coord[(b*NATOM+k)*3+2];
    float d  = sqrtf(dx*dx+dy*dy+dz*dz + 1e-12f);
    #pragma unroll
    for(int h=0;h<NHEAD;h++) out[h]=0.f;
    for(int rr=0;rr<16;rr++){
      float cen = (10.f/15.f)*rr;
      float e = __expf(-2.f*(d-cen)*(d-cen));
      #pragma unroll
      for(int h=0;h<NHEAD;h++) out[h] += e * rbfw[rr*NHEAD+h];
    }
  }
  #pragma unroll
  for(int h=0;h<NHEAD;h++)
    db[(((size_t)b*NHEAD+h)*SENC + q)*SENC + k] = out[h];
}

// ===== encoder attention: one block per (b,h); two-pass softmax in LDS =====
__global__ __launch_bounds__(128) void k_attn_enc(
    const float* __restrict__ qkv, const float* __restrict__ db,
    float* __restrict__ o_out)
{
  __shared__ float Ps[80][81];   // scores / probs (db preloaded)
  __shared__ float KV[80][64];   // K, then V
  int bh = blockIdx.x; int h = bh & 7, b = bh >> 3;
  const float* base = qkv + (size_t)b*SENC*(3*HGDIM);
  const float* dbb  = db + (size_t)bh*6400;
  int tid = threadIdx.x;
  for(int idx=tid; idx<80*64; idx+=128){
    int k = idx>>6, d = idx&63;
    KV[k][d] = base[(size_t)k*1536 + 512 + h*64 + d];
  }
  for(int idx=tid; idx<6400; idx+=128){
    int q = idx/80, k = idx - q*80;
    Ps[q][k] = dbb[idx];
  }
  __syncthreads();
  int q = tid;
  if(q < 80){
    float qr[64];
    const float* qrow = base + (size_t)q*1536 + h*64;
    #pragma unroll
    for(int d=0;d<64;d++) qr[d] = qrow[d];
    for(int k=0;k<80;k++){
      float4 s0 = {0,0,0,0};
      #pragma unroll
      for(int d=0;d<64;d+=4){
        float4 kv = *(const float4*)&KV[k][d];
        s0.x += qr[d]*kv.x; s0.y += qr[d+1]*kv.y;
        s0.z += qr[d+2]*kv.z; s0.w += qr[d+3]*kv.w;
      }
      Ps[q][k] += (s0.x+s0.y+s0.z+s0.w)*0.125f;
    }
  }
  __syncthreads();                       // all K reads done
  for(int idx=tid; idx<80*64; idx+=128){ // stage V over K
    int k = idx>>6, d = idx&63;
    KV[k][d] = base[(size_t)k*1536 + 1024 + h*64 + d];
  }
  if(q < 80){                            // softmax own row (no barrier needed)
    float m = -1e30f;
    for(int k=0;k<80;k++) m = fmaxf(m, Ps[q][k]);
    float l = 0.f;
    for(int k=0;k<80;k++){ float e = __expf(Ps[q][k]-m); Ps[q][k]=e; l+=e; }
    float inv = 1.f/l;
    for(int k=0;k<80;k++) Ps[q][k] *= inv;
  }
  __syncthreads();
  if(q < 80){
    float o[64];
    #pragma unroll
    for(int d=0;d<64;d++) o[d]=0.f;
    for(int k=0;k<80;k++){
      float p = Ps[q][k];
      #pragma unroll
      for(int d=0;d<64;d+=4){
        float4 v = *(const float4*)&KV[k][d];
        o[d] += p*v.x; o[d+1] += p*v.y; o[d+2] += p*v.z; o[d+3] += p*v.w;
      }
    }
    float* orow = o_out + ((size_t)(b*SENC+q))*HGDIM + h*64;
    #pragma unroll
    for(int d=0;d<64;d++) orow[d] = o[d];
  }
}

// ===== decoder attention: one block per (b,h); online softmax =====
__global__ __launch_bounds__(192) void k_attn_dec(
    const float* __restrict__ qkv, const float* __restrict__ real,
    float* __restrict__ o_out)
{
  __shared__ float Ks[160][32];
  __shared__ float Vs[160][32];
  __shared__ float mb[160];
  int bh = blockIdx.x; int h = bh & 7, b = bh >> 3;
  const float* base = qkv + (size_t)b*SDEC*(3*HIDDIM);
  int tid = threadIdx.x;
  for(int idx=tid; idx<160*32; idx+=192){
    int k = idx>>5, d = idx&31;
    Ks[k][d] = base[(size_t)k*768 + 256 + h*32 + d];
    Vs[k][d] = base[(size_t)k*768 + 512 + h*32 + d];
  }
  for(int k=tid;k<160;k+=192){
    int kk = (k<80)?k:k-80;
    mb[k] = (real[b*NATOM+kk]==0.f) ? -1e9f : 0.f;
  }
  __syncthreads();
  int q = tid;
  if(q < 160){
    float qr[32];
    const float* qrow = base + (size_t)q*768 + h*32;
    #pragma unroll
    for(int d=0;d<32;d++) qr[d]=qrow[d];
    float m=-1e30f, l=0.f, o[32];
    #pragma unroll
    for(int d=0;d<32;d++) o[d]=0.f;
    for(int k=0;k<160;k++){
      float4 s0 = {0,0,0,0};
      #pragma unroll
      for(int d=0;d<32;d+=4){
        float4 kv = *(const float4*)&Ks[k][d];
        s0.x += qr[d]*kv.x; s0.y += qr[d+1]*kv.y;
        s0.z += qr[d+2]*kv.z; s0.w += qr[d+3]*kv.w;
      }
      float s = (s0.x+s0.y+s0.z+s0.w)*0.17677669529663689f + mb[k];
      float mn = fmaxf(m, s);
      float c = __expf(m - mn);
      float e = __expf(s - mn);
      l = l*c + e;
      #pragma unroll
      for(int d=0;d<32;d+=4){
        float4 v = *(const float4*)&Vs[k][d];
        o[d]   = o[d]*c   + e*v.x;
        o[d+1] = o[d+1]*c + e*v.y;
        o[d+2] = o[d+2]*c + e*v.z;
        o[d+3] = o[d+3]*c + e*v.w;
      }
      m = mn;
    }
    float inv = 1.f/l;
    float* orow = o_out + ((size_t)(b*SDEC+q))*HIDDIM + h*32;
    #pragma unroll
    for(int d=0;d<32;d++) orow[d] = o[d]*inv;
  }
}

// fp32 tiled GEMM, float4 LDS: C[M,N] = epi(A[M,K] @ W[K,N]); M%64==0, N%64==0, K%16==0
__global__ __launch_bounds__(256) void k_gemm64(
    const float* __restrict__ A, const float* __restrict__ W, const float* __restrict__ bias,
    const float* __restrict__ resid, const float* __restrict__ rowscale,
    float* __restrict__ C,
    int M, int K, int Nw, int act)
{
  __shared__ float As[16][68];   // [k][m]
  __shared__ float Ws[16][68];   // [k][n]
  int tid = threadIdx.x;
  int tx = tid & 15, ty = tid >> 4;
  int row0 = blockIdx.y*64, col0 = blockIdx.x*64;
  int ar = tid >> 2, ac4 = (tid & 3)*4;     // A stage: row ar, k ac4..+3
  int wk = tid >> 4, wc4 = (tid & 15)*4;    // W stage: k wk, col wc4..+3
  float acc[4][4] = {};
  for(int k0=0;k0<K;k0+=16){
    float4 av = *(const float4*)&A[(size_t)(row0+ar)*K + k0 + ac4];
    float4 wv = *(const float4*)&W[(size_t)(k0+wk)*Nw + col0 + wc4];
    As[ac4  ][ar] = av.x;
    As[ac4+1][ar] = av.y;
    As[ac4+2][ar] = av.z;
    As[ac4+3][ar] = av.w;
    *(float4*)&Ws[wk][wc4] = wv;
    __syncthreads();
    #pragma unroll
    for(int kk=0;kk<16;kk++){
      float4 a = *(const float4*)&As[kk][ty*4];
      float4 bv = *(const float4*)&Ws[kk][tx*4];
      acc[0][0]+=a.x*bv.x; acc[0][1]+=a.x*bv.y; acc[0][2]+=a.x*bv.z; acc[0][3]+=a.x*bv.w;
      acc[1][0]+=a.y*bv.x; acc[1][1]+=a.y*bv.y; acc[1][2]+=a.y*bv.z; acc[1][3]+=a.y*bv.w;
      acc[2][0]+=a.z*bv.x; acc[2][1]+=a.z*bv.y; acc[2][2]+=a.z*bv.z; acc[2][3]+=a.z*bv.w;
      acc[3][0]+=a.w*bv.x; acc[3][1]+=a.w*bv.y; acc[3][2]+=a.w*bv.z; acc[3][3]+=a.w*bv.w;
    }
    __syncthreads();
  }
  #pragma unroll
  for(int i=0;i<4;i++){
    int row = row0 + ty*4 + i;
    float rs = rowscale ? rowscale[row] : 1.f;
    int col = col0 + tx*4;
    float4 c4;
    c4.x = acc[i][0]; c4.y = acc[i][1]; c4.z = acc[i][2]; c4.w = acc[i][3];
    if(bias){
      const float4 b4 = *(const float4*)&bias[col];
      c4.x += b4.x; c4.y += b4.y; c4.z += b4.z; c4.w += b4.w;
    }
    if(resid){
      const float4 r4 = *(const float4*)&resid[(size_t)row*Nw + col];
      c4.x += r4.x; c4.y += r4.y; c4.z += r4.z; c4.w += r4.w;
    }
    if(act==1){
      c4.x = c4.x/(1.f+__expf(-c4.x));
      c4.y = c4.y/(1.f+__expf(-c4.y));
      c4.z = c4.z/(1.f+__expf(-c4.z));
      c4.w = c4.w/(1.f+__expf(-c4.w));
    }
    c4.x *= rs; c4.y *= rs; c4.z *= rs; c4.w *= rs;
    *(float4*)&C[(size_t)row*Nw + col] = c4;
  }
}

// thread-per-output GEMM for tiny N
__global__ void k_gemm_small(const float* __restrict__ A, const float* __restrict__ W,
    const float* __restrict__ bias, float* __restrict__ C,
    int M, int K, int Nw, int act){
  int idx = blockIdx.x*256 + threadIdx.x;
  if(idx >= M*Nw) return;
  int row = idx / Nw, col = idx % Nw;
  float s = bias ? bias[col] : 0.f;
  const float* a = A + (size_t)row*K;
  for(int k=0;k<K;k++) s += a[k]*W[(size_t)k*Nw+col];
  if(act==1) s = s/(1.f+__expf(-s));
  C[idx] = s;
}

__global__ __launch_bounds__(256) void k_kl(const float* __restrict__ mom,
    const float* __restrict__ real, float* __restrict__ part){
  int i = blockIdx.x*256 + threadIdx.x;
  float s = 0.f;
  if(i < ROWS_E){
    const float* m = mom + (size_t)i*12;
    float acc = 0.f;
    #pragma unroll
    for(int d=0;d<6;d++){ float mu=m[d], lv=m[6+d]; acc += 1.f + lv - mu*mu - __expf(lv*0.69314718056f*1.4426950408889634f); }
    s = acc * real[i];
  }
  #pragma unroll
  for(int o=32;o>0;o>>=1) s += __shfl_xor(s,o);
  __shared__ float r[4];
  if((threadIdx.x&63)==0) r[threadIdx.x>>6]=s;
  __syncthreads();
  if(threadIdx.x==0) part[blockIdx.x] = r[0]+r[1]+r[2]+r[3];
}

__global__ void k_klfin(const float* __restrict__ part, float* __restrict__ o){
  float s=0.f;
  for(int i=0;i<40;i++) s += part[i];
  *o = -0.5f * (s/(float)ROWS_E) * 1e-6f;
}

__global__ __launch_bounds__(256) void k_build_x(
  const float* __restrict__ coord_t, const float* __restrict__ atomics_t, const float* __restrict__ tin,
  const float* __restrict__ qout_w, const float* __restrict__ qout_b, const float* __restrict__ cond,
  const float* __restrict__ lin_w, const float* __restrict__ atom_emb,
  const float* __restrict__ mom, const float* __restrict__ real, float* __restrict__ x)
{
  int idx = blockIdx.x*256 + threadIdx.x;
  if(idx >= NBATCH*SDEC*HIDDIM) return;
  int c = idx & 255; int rowg = idx >> 8; int s = rowg % SDEC; int b = rowg / SDEC;
  int n = (s<NATOM)? s : s-NATOM;
  int j = c >> 1;
  float div = __expf(-(float)(2*j) * (9.210340371976184f/256.f));
  float ang = (float)n * div;
  float pe = (c & 1) ? __cosf(ang) : __sinf(ang);
  float rl = real[b*NATOM + n];
  float v;
  if(s < NATOM){
    int rown = b*NATOM + n;
    float cl = 0.f;
    #pragma unroll
    for(int a=0;a<3;a++) cl += coord_t[rown*3+a] * lin_w[a*HIDDIM+c];
    int bi=0; float bv = atomics_t[rown*16];
    for(int a=1;a<16;a++){ float vv=atomics_t[rown*16+a]; if(vv>bv){bv=vv; bi=a;} }
    float ae = atom_emb[bi*HIDDIM+c];
    float tb = tin[b];
    float tf;
    if(c < 128){
      float fr = __expf(-(float)c * (5.298317366548036f/128.f));
      tf = __sinf(tb*200.f*fr);
    } else {
      float fr = __expf(-(float)(c-128) * (5.298317366548036f/128.f));
      tf = __cosf(tb*200.f*fr);
    }
    v = (cl + ae + pe + tf)*rl + cond[c];
  } else {
    int rown = b*NATOM + n;
    const float* mp = mom + (size_t)rown*12;
    float s2 = qout_b[c];
    #pragma unroll
    for(int d=0;d<6;d++) s2 += mp[d]*qout_w[d*HIDDIM+c];
    v = (s2 + pe)*rl + cond[HIDDIM+c];
  }
  x[idx] = v;
}

__global__ void k_hout(const float* __restrict__ x, const float* __restrict__ real,
                       float* __restrict__ h_out){
  int idx = blockIdx.x*256 + threadIdx.x;
  if(idx >= ROWS_E*HIDDIM) return;
  int c = idx & 255, row = idx >> 8;
  int n = row % NATOM, b = row / NATOM;
  h_out[idx] = x[((size_t)(b*SDEC+n))*HIDDIM + c] * real[row];
}

// ---------------- launch ----------------
extern "C" void kernel_launch(void* const* d_in, const int* in_sizes, int n_in,
                              void* d_out, int out_size, void* d_ws, size_t ws_size,
                              hipStream_t stream){
  (void)in_sizes; (void)n_in; (void)out_size;
  const float* coord_ori   = (const float*)d_in[0];
  const float* atomics_ori = (const float*)d_in[1];
  const unsigned char* pmask = (const unsigned char*)d_in[2];
  const float* coord_t     = (const float*)d_in[3];
  const float* atomics_t   = (const float*)d_in[4];
  const float* t_in        = (const float*)d_in[5];
  const float* enc_embed_w = (const float*)d_in[6];
  const float* rbf_w       = (const float*)d_in[7];
  const float* e_qkv_w=(const float*)d_in[8];  const float* e_qkv_b=(const float*)d_in[9];
  const float* e_out_w=(const float*)d_in[10]; const float* e_out_b=(const float*)d_in[11];
  const float* e_ff1_w=(const float*)d_in[12]; const float* e_ff1_b=(const float*)d_in[13];
  const float* e_ff2_w=(const float*)d_in[14]; const float* e_ff2_b=(const float*)d_in[15];
  const float* e_ln1_g=(const float*)d_in[16]; const float* e_ln1_b=(const float*)d_in[17];
  const float* e_ln2_g=(const float*)d_in[18]; const float* e_ln2_b=(const float*)d_in[19];
  const float* enc_proj_w=(const float*)d_in[20];
  const float* quant_w=(const float*)d_in[21]; const float* quant_b=(const float*)d_in[22];
  const float* qout_w=(const float*)d_in[23];  const float* qout_b=(const float*)d_in[24];
  const float* cond_embed=(const float*)d_in[25];
  const float* lin_embed_w=(const float*)d_in[26];
  const float* atom_embed=(const float*)d_in[27];
  const float* d_qkv_w=(const float*)d_in[28]; const float* d_qkv_b=(const float*)d_in[29];
  const float* d_ow   =(const float*)d_in[30]; const float* d_ob   =(const float*)d_in[31];
  const float* d_ff1_w=(const float*)d_in[32]; const float* d_ff1_b=(const float*)d_in[33];
  const float* d_ff2_w=(const float*)d_in[34]; const float* d_ff2_b=(const float*)d_in[35];
  const float* d_ln1_g=(const float*)d_in[36]; const float* d_ln1_b=(const float*)d_in[37];
  const float* d_ln2_g=(const float*)d_in[38]; const float* d_ln2_b=(const float*)d_in[39];
  const float* oc_ln_g=(const float*)d_in[40]; const float* oc_ln_b=(const float*)d_in[41];
  const float* oc_w   =(const float*)d_in[42];
  const float* oa1_w  =(const float*)d_in[43]; const float* oa1_b=(const float*)d_in[44];
  const float* oa2_w  =(const float*)d_in[45]; const float* oa2_b=(const float*)d_in[46];

  float* ws   = (float*)d_ws;
  float* real = ws + OFF_REAL;
  int*   flag = (int*)(ws + OFF_FLAG);
  float* h    = ws + OFF_H;
  float* lnb  = ws + OFF_LN;
  float* big  = ws + OFF_BIG;
  float* ao   = ws + OFF_AO;
  float* db   = ws + OFF_DB;
  float* rep  = ws + OFF_REP;
  float* mom  = ws + OFF_MOM;
  float* klp  = ws + OFF_KL;
  float* out  = (float*)d_out;

  if(ws_size < NEED_BYTES){
    k_wsfail<<<1,64,0,stream>>>(out, 1.0e6f + (float)(ws_size>>20));
    return;
  }

  k_maskmode<<<1,256,0,stream>>>(pmask, flag);
  k_real <<<40,   256, 0, stream>>>(pmask, flag, real);
  k_embed<<<20480,256, 0, stream>>>(atomics_ori, enc_embed_w, h);

  // ===== encoder =====
  for(int i=0;i<4;i++){
    k_ln<<<ROWS_E,256,0,stream>>>(h, e_ln1_g+i*HGDIM, e_ln1_b+i*HGDIM, lnb, HGDIM);
    k_gemm64<<<dim3(24,160),256,0,stream>>>(lnb, e_qkv_w+(size_t)i*HGDIM*3*HGDIM,
        e_qkv_b+i*3*HGDIM, nullptr, nullptr, big, ROWS_E, HGDIM, 3*HGDIM, 0);
    k_db<<<3200,256,0,stream>>>(coord_ori, real, rbf_w + i*16*NHEAD, db);
    k_attn_enc<<<NBATCH*NHEAD,128,0,stream>>>(big, db, ao);
    k_gemm64<<<dim3(8,160),256,0,stream>>>(ao, e_out_w+(size_t)i*HGDIM*HGDIM,
        e_out_b+i*HGDIM, h, nullptr, h, ROWS_E, HGDIM, HGDIM, 0);
    k_ln<<<ROWS_E,256,0,stream>>>(h, e_ln2_g+i*HGDIM, e_ln2_b+i*HGDIM, lnb, HGDIM);
    k_gemm64<<<dim3(32,160),256,0,stream>>>(lnb, e_ff1_w+(size_t)i*HGDIM*4*HGDIM,
        e_ff1_b+i*4*HGDIM, nullptr, nullptr, big, ROWS_E, HGDIM, 4*HGDIM, 1);
    k_gemm64<<<dim3(8,160),256,0,stream>>>(big, e_ff2_w+(size_t)i*4*HGDIM*HGDIM,
        e_ff2_b+i*HGDIM, h, nullptr, h, ROWS_E, 4*HGDIM, HGDIM, 0);
  }

  k_gemm64<<<dim3(4,160),256,0,stream>>>(h, enc_proj_w, nullptr, nullptr, real,
      rep, ROWS_E, HGDIM, HIDDIM, 0);
  k_gemm_small<<<480,256,0,stream>>>(rep, quant_w, quant_b, mom, ROWS_E, HIDDIM, 12, 0);
  k_kl   <<<40,256,0,stream>>>(mom, real, klp);
  k_klfin<<<1,1,0,stream>>>(klp, out + 194560);

  k_build_x<<<20480,256,0,stream>>>(coord_t, atomics_t, t_in, qout_w, qout_b,
      cond_embed, lin_embed_w, atom_embed, mom, real, h);

  // ===== decoder =====
  for(int i=0;i<8;i++){
    k_ln<<<ROWS_D,256,0,stream>>>(h, d_ln1_g+i*HIDDIM, d_ln1_b+i*HIDDIM, lnb, HIDDIM);
    k_gemm64<<<dim3(12,320),256,0,stream>>>(lnb, d_qkv_w+(size_t)i*HIDDIM*3*HIDDIM,
        d_qkv_b+i*3*HIDDIM, nullptr, nullptr, big, ROWS_D, HIDDIM, 3*HIDDIM, 0);
    k_attn_dec<<<NBATCH*NHEAD,192,0,stream>>>(big, real, ao);
    k_gemm64<<<dim3(4,320),256,0,stream>>>(ao, d_ow+(size_t)i*HIDDIM*HIDDIM,
        d_ob+i*HIDDIM, h, nullptr, h, ROWS_D, HIDDIM, HIDDIM, 0);
    k_ln<<<ROWS_D,256,0,stream>>>(h, d_ln2_g+i*HIDDIM, d_ln2_b+i*HIDDIM, lnb, HIDDIM);
    k_gemm64<<<dim3(16,320),256,0,stream>>>(lnb, d_ff1_w+(size_t)i*HIDDIM*4*HIDDIM,
        d_ff1_b+i*4*HIDDIM, nullptr, nullptr, big, ROWS_D, HIDDIM, 4*HIDDIM, 1);
    k_gemm64<<<dim3(4,320),256,0,stream>>>(big, d_ff2_w+(size_t)i*4*HIDDIM*HIDDIM,
        d_ff2_b+i*HIDDIM, h, nullptr, h, ROWS_D, 4*HIDDIM, HIDDIM, 0);
  }

  // ===== heads =====
  k_hout<<<10240,256,0,stream>>>(h, real, rep);
  k_ln<<<ROWS_E,256,0,stream>>>(rep, oc_ln_g, oc_ln_b, lnb, HIDDIM);
  k_gemm_small<<<120,256,0,stream>>>(lnb, oc_w, nullptr, out, ROWS_E, HIDDIM, 3, 0);
  k_gemm64<<<dim3(4,160),256,0,stream>>>(rep, oa1_w, oa1_b, nullptr, nullptr,
      big, ROWS_E, HIDDIM, HIDDIM, 1);
  k_gemm_small<<<640,256,0,stream>>>(big, oa2_w, oa2_b, out + 30720,
      ROWS_E, HIDDIM, 16, 0);
}

// Round 10
// 9293.121 us; speedup vs baseline: 1.6915x; 1.0465x over previous
//
#include <hip/hip_runtime.h>
#include <hip/hip_bf16.h>
#include <math.h>

#define NBATCH 128
#define NATOM  80
#define SENC   80
#define SDEC   160
#define HGDIM  512
#define HIDDIM 256
#define NHEAD  8
#define ROWS_E (NBATCH*NATOM)   /* 10240 */
#define ROWS_D (NBATCH*SDEC)    /* 20480 */

// ---------------- workspace layout (float offsets) ----------------
#define OFF_REAL 0ull
#define OFF_FLAG 10240ull
#define OFF_H    16384ull
#define OFF_LN   (OFF_H  + 5242880ull)
#define OFF_BIG  (OFF_LN + 5242880ull)
#define OFF_AO   (OFF_BIG+ 20971520ull)
#define OFF_DB   (OFF_AO + 5242880ull)
#define OFF_REP  (OFF_DB + 6553600ull)
#define OFF_MOM  (OFF_REP+ 2621440ull)
#define OFF_KL   (OFF_MOM+ 122880ull)
#define NEED_BYTES 184058112ull

// mask dtype probe, atomic-free. flag=1 -> bool bytes, 0 -> int32.
__global__ void k_maskmode(const unsigned char* __restrict__ m, int* __restrict__ flag){
  __shared__ int sh[256];
  int loc = 0;
  for(int i=threadIdx.x; i<ROWS_E; i+=256)
    if((i&3)!=0 && m[i]) loc = 1;
  sh[threadIdx.x] = loc;
  __syncthreads();
  if(threadIdx.x==0){
    int a=0;
    for(int j=0;j<256;j++) a |= sh[j];
    *flag = a;
  }
}

__global__ void k_real(const unsigned char* __restrict__ m, const int* __restrict__ flag,
                       float* __restrict__ real){
  int i = blockIdx.x*256 + threadIdx.x;
  if(i >= ROWS_E) return;
  int v = (*flag) ? (int)m[i] : ((const int*)m)[i];
  real[i] = v ? 0.f : 1.f;
}

__global__ void k_wsfail(float* __restrict__ out, float code){
  if(threadIdx.x==0) out[0] = code;
}

__global__ void k_embed(const float* __restrict__ atom, const float* __restrict__ W,
                        float* __restrict__ h){
  int idx = blockIdx.x*256 + threadIdx.x;
  if(idx >= ROWS_E*HGDIM) return;
  int row = idx >> 9, c = idx & 511;
  float s = 0.f;
  #pragma unroll
  for(int a=0;a<16;a++) s += atom[row*16+a] * W[a*HGDIM+c];
  h[idx] = s;
}

__global__ __launch_bounds__(256) void k_ln(const float* __restrict__ x,
    const float* __restrict__ g, const float* __restrict__ bta,
    float* __restrict__ y, int D){
  size_t row = blockIdx.x;
  const float* xr = x + row*D;
  float* yr = y + row*D;
  int t = threadIdx.x;
  float s=0.f, s2=0.f;
  for(int c=t;c<D;c+=256){ float v=xr[c]; s+=v; s2+=v*v; }
  #pragma unroll
  for(int o=32;o>0;o>>=1){ s += __shfl_xor(s,o); s2 += __shfl_xor(s2,o); }
  __shared__ float ra[4], rb[4];
  int w = t>>6;
  if((t&63)==0){ ra[w]=s; rb[w]=s2; }
  __syncthreads();
  float ts  = ra[0]+ra[1]+ra[2]+ra[3];
  float ts2 = rb[0]+rb[1]+rb[2]+rb[3];
  float mean = ts / D;
  float var  = fmaxf(ts2 / D - mean*mean, 0.f);
  float inv  = rsqrtf(var + 1e-5f);
  for(int c=t;c<D;c+=256){
    float v = (xr[c]-mean)*inv;
    yr[c] = v*g[c] + bta[c];
  }
}

// rbf attention bias for one encoder block: db[b][h][q][k]
__global__ void k_db(const float* __restrict__ coord, const float* __restrict__ real,
                     const float* __restrict__ rbfw, float* __restrict__ db){
  int idx = blockIdx.x*256 + threadIdx.x;
  if(idx >= NBATCH*SENC*SENC) return;
  int b = idx/(SENC*SENC), r = idx%(SENC*SENC), q = r/SENC, k = r%SENC;
  float out[NHEAD];
  bool masked = (real[b*NATOM+k]==0.f) || (k==q);
  if(masked){
    #pragma unroll
    for(int h=0;h<NHEAD;h++) out[h] = -1e9f;
  } else {
    float dx = coord[(b*NATOM+q)*3+0] - coord[(b*NATOM+k)*3+0];
    float dy = coord[(b*NATOM+q)*3+1] - coord[(b*NATOM+k)*3+1];
    float dz = coord[(b*NATOM+q)*3+2] - coord[(b*NATOM+k)*3+2];
    float d  = sqrtf(dx*dx+dy*dy+dz*dz + 1e-12f);
    #pragma unroll
    for(int h=0;h<NHEAD;h++) out[h]=0.f;
    for(int rr=0;rr<16;rr++){
      float cen = (10.f/15.f)*rr;
      float e = __expf(-2.f*(d-cen)*(d-cen));
      #pragma unroll
      for(int h=0;h<NHEAD;h++) out[h] += e * rbfw[rr*NHEAD+h];
    }
  }
  #pragma unroll
  for(int h=0;h<NHEAD;h++)
    db[(((size_t)b*NHEAD+h)*SENC + q)*SENC + k] = out[h];
}

// ===== encoder attention: one block per (b,h); 320 threads, thread=(q,quarter) =====
__global__ __launch_bounds__(320) void k_attn_enc(
    const float* __restrict__ qkv, const float* __restrict__ db,
    float* __restrict__ o_out)
{
  __shared__ float Ps[80][81];   // db -> scores -> probs
  __shared__ float KV[80][64];   // K, then V
  int bh = blockIdx.x; int h = bh & 7, b = bh >> 3;
  const float* base = qkv + (size_t)b*SENC*1536;
  const float* dbb  = db + (size_t)bh*6400;
  int tid = threadIdx.x;
  for(int idx=tid; idx<80*64; idx+=320){
    int k = idx>>6, d = idx&63;
    KV[k][d] = base[(size_t)k*1536 + 512 + h*64 + d];
  }
  for(int idx=tid; idx<6400; idx+=320){
    int q2 = idx/80, k = idx - q2*80;
    Ps[q2][k] = dbb[idx];
  }
  __syncthreads();
  int q = tid >> 2, part = tid & 3;
  float qr[64];
  {
    const float* qrow = base + (size_t)q*1536 + h*64;
    #pragma unroll
    for(int d=0;d<64;d+=4){
      float4 v = *(const float4*)&qrow[d];
      qr[d]=v.x; qr[d+1]=v.y; qr[d+2]=v.z; qr[d+3]=v.w;
    }
  }
  int k0 = part*20;
  for(int k=k0;k<k0+20;k++){
    float4 s = {0,0,0,0};
    #pragma unroll
    for(int d=0;d<64;d+=4){
      float4 kv = *(const float4*)&KV[k][d];
      s.x += qr[d]*kv.x; s.y += qr[d+1]*kv.y;
      s.z += qr[d+2]*kv.z; s.w += qr[d+3]*kv.w;
    }
    Ps[q][k] += (s.x+s.y+s.z+s.w)*0.125f;
  }
  __syncthreads();
  // stage V over K; softmax rows in parallel (disjoint LDS)
  for(int idx=tid; idx<80*64; idx+=320){
    int k = idx>>6, d = idx&63;
    KV[k][d] = base[(size_t)k*1536 + 1024 + h*64 + d];
  }
  if(tid < 80){
    int qq = tid;
    float m = -1e30f;
    for(int k=0;k<80;k++) m = fmaxf(m, Ps[qq][k]);
    float l = 0.f;
    for(int k=0;k<80;k++){ float e = __expf(Ps[qq][k]-m); Ps[qq][k]=e; l+=e; }
    float inv = 1.f/l;
    for(int k=0;k<80;k++) Ps[qq][k] *= inv;
  }
  __syncthreads();
  int dp = part*16;
  float o[16];
  #pragma unroll
  for(int j=0;j<16;j++) o[j]=0.f;
  for(int k=0;k<80;k++){
    float p = Ps[q][k];
    #pragma unroll
    for(int j=0;j<16;j+=4){
      float4 v = *(const float4*)&KV[k][dp+j];
      o[j] += p*v.x; o[j+1] += p*v.y; o[j+2] += p*v.z; o[j+3] += p*v.w;
    }
  }
  float* orow = o_out + ((size_t)(b*SENC+q))*HGDIM + h*64 + dp;
  #pragma unroll
  for(int j=0;j<16;j+=4){
    float4 v; v.x=o[j]; v.y=o[j+1]; v.z=o[j+2]; v.w=o[j+3];
    *(float4*)&orow[j] = v;
  }
}

// ===== decoder attention: one block per (b,h); online softmax =====
__global__ __launch_bounds__(192) void k_attn_dec(
    const float* __restrict__ qkv, const float* __restrict__ real,
    float* __restrict__ o_out)
{
  __shared__ float Ks[160][32];
  __shared__ float Vs[160][32];
  __shared__ float mb[160];
  int bh = blockIdx.x; int h = bh & 7, b = bh >> 3;
  const float* base = qkv + (size_t)b*SDEC*768;
  int tid = threadIdx.x;
  for(int idx=tid; idx<160*32; idx+=192){
    int k = idx>>5, d = idx&31;
    Ks[k][d] = base[(size_t)k*768 + 256 + h*32 + d];
    Vs[k][d] = base[(size_t)k*768 + 512 + h*32 + d];
  }
  for(int k=tid;k<160;k+=192){
    int kk = (k<80)?k:k-80;
    mb[k] = (real[b*NATOM+kk]==0.f) ? -1e9f : 0.f;
  }
  __syncthreads();
  int q = tid;
  if(q < 160){
    float qr[32];
    const float* qrow = base + (size_t)q*768 + h*32;
    #pragma unroll
    for(int d=0;d<32;d++) qr[d]=qrow[d];
    float m=-1e30f, l=0.f, o[32];
    #pragma unroll
    for(int d=0;d<32;d++) o[d]=0.f;
    for(int k=0;k<160;k++){
      float4 s0 = {0,0,0,0};
      #pragma unroll
      for(int d=0;d<32;d+=4){
        float4 kv = *(const float4*)&Ks[k][d];
        s0.x += qr[d]*kv.x; s0.y += qr[d+1]*kv.y;
        s0.z += qr[d+2]*kv.z; s0.w += qr[d+3]*kv.w;
      }
      float s = (s0.x+s0.y+s0.z+s0.w)*0.17677669529663689f + mb[k];
      float mn = fmaxf(m, s);
      float c = __expf(m - mn);
      float e = __expf(s - mn);
      l = l*c + e;
      #pragma unroll
      for(int d=0;d<32;d+=4){
        float4 v = *(const float4*)&Vs[k][d];
        o[d]   = o[d]*c   + e*v.x;
        o[d+1] = o[d+1]*c + e*v.y;
        o[d+2] = o[d+2]*c + e*v.z;
        o[d+3] = o[d+3]*c + e*v.w;
      }
      m = mn;
    }
    float inv = 1.f/l;
    float* orow = o_out + ((size_t)(b*SDEC+q))*HIDDIM + h*32;
    #pragma unroll
    for(int d=0;d<32;d++) orow[d] = o[d]*inv;
  }
}

// fp32 tiled GEMM, 128x128 tile, 8x8 accum: C = epi(A[M,K]@W[K,N]); M,N %128, K %16
__global__ __launch_bounds__(256) void k_gemm128(
    const float* __restrict__ A, const float* __restrict__ W, const float* __restrict__ bias,
    const float* __restrict__ resid, const float* __restrict__ rowscale,
    float* __restrict__ C,
    int M, int K, int Nw, int act)
{
  __shared__ float As[16][132];  // [k][m]
  __shared__ float Ws[16][132];  // [k][n]
  int tid = threadIdx.x;
  int tx = tid & 15, ty = tid >> 4;
  int row0 = blockIdx.y*128, col0 = blockIdx.x*128;
  int arow = tid >> 2, akq = (tid & 3)*4;   // A: rows arow, arow+64; k-quads
  int wk = tid >> 4, wc = (tid & 15)*4;     // W: k row wk, cols wc, wc+64
  float acc[8][8] = {};
  for(int k0=0;k0<K;k0+=16){
    float4 a0 = *(const float4*)&A[(size_t)(row0+arow)*K + k0 + akq];
    float4 a1 = *(const float4*)&A[(size_t)(row0+arow+64)*K + k0 + akq];
    float4 w0 = *(const float4*)&W[(size_t)(k0+wk)*Nw + col0 + wc];
    float4 w1 = *(const float4*)&W[(size_t)(k0+wk)*Nw + col0 + 64 + wc];
    As[akq  ][arow] = a0.x; As[akq+1][arow] = a0.y;
    As[akq+2][arow] = a0.z; As[akq+3][arow] = a0.w;
    As[akq  ][arow+64] = a1.x; As[akq+1][arow+64] = a1.y;
    As[akq+2][arow+64] = a1.z; As[akq+3][arow+64] = a1.w;
    *(float4*)&Ws[wk][wc] = w0;
    *(float4*)&Ws[wk][64+wc] = w1;
    __syncthreads();
    #pragma unroll
    for(int kk=0;kk<16;kk++){
      float4 a_0 = *(const float4*)&As[kk][ty*4];
      float4 a_1 = *(const float4*)&As[kk][64+ty*4];
      float4 b_0 = *(const float4*)&Ws[kk][tx*4];
      float4 b_1 = *(const float4*)&Ws[kk][64+tx*4];
      float a[8] = {a_0.x,a_0.y,a_0.z,a_0.w,a_1.x,a_1.y,a_1.z,a_1.w};
      float bb[8] = {b_0.x,b_0.y,b_0.z,b_0.w,b_1.x,b_1.y,b_1.z,b_1.w};
      #pragma unroll
      for(int i=0;i<8;i++)
        #pragma unroll
        for(int j=0;j<8;j++) acc[i][j] += a[i]*bb[j];
    }
    __syncthreads();
  }
  #pragma unroll
  for(int i=0;i<8;i++){
    int row = row0 + ((i<4)? (ty*4+i) : (64+ty*4+(i-4)));
    float rs = rowscale ? rowscale[row] : 1.f;
    #pragma unroll
    for(int jh=0;jh<2;jh++){
      int col = col0 + jh*64 + tx*4;
      float4 c4;
      c4.x = acc[i][jh*4]; c4.y = acc[i][jh*4+1];
      c4.z = acc[i][jh*4+2]; c4.w = acc[i][jh*4+3];
      if(bias){
        const float4 b4 = *(const float4*)&bias[col];
        c4.x += b4.x; c4.y += b4.y; c4.z += b4.z; c4.w += b4.w;
      }
      if(resid){
        const float4 r4 = *(const float4*)&resid[(size_t)row*Nw + col];
        c4.x += r4.x; c4.y += r4.y; c4.z += r4.z; c4.w += r4.w;
      }
      if(act==1){
        c4.x = c4.x/(1.f+__expf(-c4.x));
        c4.y = c4.y/(1.f+__expf(-c4.y));
        c4.z = c4.z/(1.f+__expf(-c4.z));
        c4.w = c4.w/(1.f+__expf(-c4.w));
      }
      c4.x *= rs; c4.y *= rs; c4.z *= rs; c4.w *= rs;
      *(float4*)&C[(size_t)row*Nw + col] = c4;
    }
  }
}

// thread-per-output GEMM for tiny N
__global__ void k_gemm_small(const float* __restrict__ A, const float* __restrict__ W,
    const float* __restrict__ bias, float* __restrict__ C,
    int M, int K, int Nw, int act){
  int idx = blockIdx.x*256 + threadIdx.x;
  if(idx >= M*Nw) return;
  int row = idx / Nw, col = idx % Nw;
  float s = bias ? bias[col] : 0.f;
  const float* a = A + (size_t)row*K;
  for(int k=0;k<K;k++) s += a[k]*W[(size_t)k*Nw+col];
  if(act==1) s = s/(1.f+__expf(-s));
  C[idx] = s;
}

__global__ __launch_bounds__(256) void k_kl(const float* __restrict__ mom,
    const float* __restrict__ real, float* __restrict__ part){
  int i = blockIdx.x*256 + threadIdx.x;
  float s = 0.f;
  if(i < ROWS_E){
    const float* m = mom + (size_t)i*12;
    float acc = 0.f;
    #pragma unroll
    for(int d=0;d<6;d++){ float mu=m[d], lv=m[6+d]; acc += 1.f + lv - mu*mu - expf(lv); }
    s = acc * real[i];
  }
  #pragma unroll
  for(int o=32;o>0;o>>=1) s += __shfl_xor(s,o);
  __shared__ float r[4];
  if((threadIdx.x&63)==0) r[threadIdx.x>>6]=s;
  __syncthreads();
  if(threadIdx.x==0) part[blockIdx.x] = r[0]+r[1]+r[2]+r[3];
}

__global__ void k_klfin(const float* __restrict__ part, float* __restrict__ o){
  float s=0.f;
  for(int i=0;i<40;i++) s += part[i];
  *o = -0.5f * (s/(float)ROWS_E) * 1e-6f;
}

__global__ __launch_bounds__(256) void k_build_x(
  const float* __restrict__ coord_t, const float* __restrict__ atomics_t, const float* __restrict__ tin,
  const float* __restrict__ qout_w, const float* __restrict__ qout_b, const float* __restrict__ cond,
  const float* __restrict__ lin_w, const float* __restrict__ atom_emb,
  const float* __restrict__ mom, const float* __restrict__ real, float* __restrict__ x)
{
  int idx = blockIdx.x*256 + threadIdx.x;
  if(idx >= NBATCH*SDEC*HIDDIM) return;
  int c = idx & 255; int rowg = idx >> 8; int s = rowg % SDEC; int b = rowg / SDEC;
  int n = (s<NATOM)? s : s-NATOM;
  int j = c >> 1;
  float div = __expf(-(float)(2*j) * (9.210340371976184f/256.f));
  float ang = (float)n * div;
  float pe = (c & 1) ? __cosf(ang) : __sinf(ang);
  float rl = real[b*NATOM + n];
  float v;
  if(s < NATOM){
    int rown = b*NATOM + n;
    float cl = 0.f;
    #pragma unroll
    for(int a=0;a<3;a++) cl += coord_t[rown*3+a] * lin_w[a*HIDDIM+c];
    int bi=0; float bv = atomics_t[rown*16];
    for(int a=1;a<16;a++){ float vv=atomics_t[rown*16+a]; if(vv>bv){bv=vv; bi=a;} }
    float ae = atom_emb[bi*HIDDIM+c];
    float tb = tin[b];
    float tf;
    if(c < 128){
      float fr = __expf(-(float)c * (5.298317366548036f/128.f));
      tf = __sinf(tb*200.f*fr);
    } else {
      float fr = __expf(-(float)(c-128) * (5.298317366548036f/128.f));
      tf = __cosf(tb*200.f*fr);
    }
    v = (cl + ae + pe + tf)*rl + cond[c];
  } else {
    int rown = b*NATOM + n;
    const float* mp = mom + (size_t)rown*12;
    float s2 = qout_b[c];
    #pragma unroll
    for(int d=0;d<6;d++) s2 += mp[d]*qout_w[d*HIDDIM+c];
    v = (s2 + pe)*rl + cond[HIDDIM+c];
  }
  x[idx] = v;
}

__global__ void k_hout(const float* __restrict__ x, const float* __restrict__ real,
                       float* __restrict__ h_out){
  int idx = blockIdx.x*256 + threadIdx.x;
  if(idx >= ROWS_E*HIDDIM) return;
  int c = idx & 255, row = idx >> 8;
  int n = row % NATOM, b = row / NATOM;
  h_out[idx] = x[((size_t)(b*SDEC+n))*HIDDIM + c] * real[row];
}

// ---------------- launch ----------------
extern "C" void kernel_launch(void* const* d_in, const int* in_sizes, int n_in,
                              void* d_out, int out_size, void* d_ws, size_t ws_size,
                              hipStream_t stream){
  (void)in_sizes; (void)n_in; (void)out_size;
  const float* coord_ori   = (const float*)d_in[0];
  const float* atomics_ori = (const float*)d_in[1];
  const unsigned char* pmask = (const unsigned char*)d_in[2];
  const float* coord_t     = (const float*)d_in[3];
  const float* atomics_t   = (const float*)d_in[4];
  const float* t_in        = (const float*)d_in[5];
  const float* enc_embed_w = (const float*)d_in[6];
  const float* rbf_w       = (const float*)d_in[7];
  const float* e_qkv_w=(const float*)d_in[8];  const float* e_qkv_b=(const float*)d_in[9];
  const float* e_out_w=(const float*)d_in[10]; const float* e_out_b=(const float*)d_in[11];
  const float* e_ff1_w=(const float*)d_in[12]; const float* e_ff1_b=(const float*)d_in[13];
  const float* e_ff2_w=(const float*)d_in[14]; const float* e_ff2_b=(const float*)d_in[15];
  const float* e_ln1_g=(const float*)d_in[16]; const float* e_ln1_b=(const float*)d_in[17];
  const float* e_ln2_g=(const float*)d_in[18]; const float* e_ln2_b=(const float*)d_in[19];
  const float* enc_proj_w=(const float*)d_in[20];
  const float* quant_w=(const float*)d_in[21]; const float* quant_b=(const float*)d_in[22];
  const float* qout_w=(const float*)d_in[23];  const float* qout_b=(const float*)d_in[24];
  const float* cond_embed=(const float*)d_in[25];
  const float* lin_embed_w=(const float*)d_in[26];
  const float* atom_embed=(const float*)d_in[27];
  const float* d_qkv_w=(const float*)d_in[28]; const float* d_qkv_b=(const float*)d_in[29];
  const float* d_ow   =(const float*)d_in[30]; const float* d_ob   =(const float*)d_in[31];
  const float* d_ff1_w=(const float*)d_in[32]; const float* d_ff1_b=(const float*)d_in[33];
  const float* d_ff2_w=(const float*)d_in[34]; const float* d_ff2_b=(const float*)d_in[35];
  const float* d_ln1_g=(const float*)d_in[36]; const float* d_ln1_b=(const float*)d_in[37];
  const float* d_ln2_g=(const float*)d_in[38]; const float* d_ln2_b=(const float*)d_in[39];
  const float* oc_ln_g=(const float*)d_in[40]; const float* oc_ln_b=(const float*)d_in[41];
  const float* oc_w   =(const float*)d_in[42];
  const float* oa1_w  =(const float*)d_in[43]; const float* oa1_b=(const float*)d_in[44];
  const float* oa2_w  =(const float*)d_in[45]; const float* oa2_b=(const float*)d_in[46];

  float* ws   = (float*)d_ws;
  float* real = ws + OFF_REAL;
  int*   flag = (int*)(ws + OFF_FLAG);
  float* h    = ws + OFF_H;
  float* lnb  = ws + OFF_LN;
  float* big  = ws + OFF_BIG;
  float* ao   = ws + OFF_AO;
  float* db   = ws + OFF_DB;
  float* rep  = ws + OFF_REP;
  float* mom  = ws + OFF_MOM;
  float* klp  = ws + OFF_KL;
  float* out  = (float*)d_out;

  if(ws_size < NEED_BYTES){
    k_wsfail<<<1,64,0,stream>>>(out, 1.0e6f + (float)(ws_size>>20));
    return;
  }

  k_maskmode<<<1,256,0,stream>>>(pmask, flag);
  k_real <<<40,   256, 0, stream>>>(pmask, flag, real);
  k_embed<<<20480,256, 0, stream>>>(atomics_ori, enc_embed_w, h);

  // ===== encoder =====
  for(int i=0;i<4;i++){
    k_ln<<<ROWS_E,256,0,stream>>>(h, e_ln1_g+i*HGDIM, e_ln1_b+i*HGDIM, lnb, HGDIM);
    k_gemm128<<<dim3(12,80),256,0,stream>>>(lnb, e_qkv_w+(size_t)i*HGDIM*3*HGDIM,
        e_qkv_b+i*3*HGDIM, nullptr, nullptr, big, ROWS_E, HGDIM, 3*HGDIM, 0);
    k_db<<<3200,256,0,stream>>>(coord_ori, real, rbf_w + i*16*NHEAD, db);
    k_attn_enc<<<NBATCH*NHEAD,320,0,stream>>>(big, db, ao);
    k_gemm128<<<dim3(4,80),256,0,stream>>>(ao, e_out_w+(size_t)i*HGDIM*HGDIM,
        e_out_b+i*HGDIM, h, nullptr, h, ROWS_E, HGDIM, HGDIM, 0);
    k_ln<<<ROWS_E,256,0,stream>>>(h, e_ln2_g+i*HGDIM, e_ln2_b+i*HGDIM, lnb, HGDIM);
    k_gemm128<<<dim3(16,80),256,0,stream>>>(lnb, e_ff1_w+(size_t)i*HGDIM*4*HGDIM,
        e_ff1_b+i*4*HGDIM, nullptr, nullptr, big, ROWS_E, HGDIM, 4*HGDIM, 1);
    k_gemm128<<<dim3(4,80),256,0,stream>>>(big, e_ff2_w+(size_t)i*4*HGDIM*HGDIM,
        e_ff2_b+i*HGDIM, h, nullptr, h, ROWS_E, 4*HGDIM, HGDIM, 0);
  }

  k_gemm128<<<dim3(2,80),256,0,stream>>>(h, enc_proj_w, nullptr, nullptr, real,
      rep, ROWS_E, HGDIM, HIDDIM, 0);
  k_gemm_small<<<480,256,0,stream>>>(rep, quant_w, quant_b, mom, ROWS_E, HIDDIM, 12, 0);
  k_kl   <<<40,256,0,stream>>>(mom, real, klp);
  k_klfin<<<1,1,0,stream>>>(klp, out + 194560);

  k_build_x<<<20480,256,0,stream>>>(coord_t, atomics_t, t_in, qout_w, qout_b,
      cond_embed, lin_embed_w, atom_embed, mom, real, h);

  // ===== decoder =====
  for(int i=0;i<8;i++){
    k_ln<<<ROWS_D,256,0,stream>>>(h, d_ln1_g+i*HIDDIM, d_ln1_b+i*HIDDIM, lnb, HIDDIM);
    k_gemm128<<<dim3(6,160),256,0,stream>>>(lnb, d_qkv_w+(size_t)i*HIDDIM*3*HIDDIM,
        d_qkv_b+i*3*HIDDIM, nullptr, nullptr, big, ROWS_D, HIDDIM, 3*HIDDIM, 0);
    k_attn_dec<<<NBATCH*NHEAD,192,0,stream>>>(big, real, ao);
    k_gemm128<<<dim3(2,160),256,0,stream>>>(ao, d_ow+(size_t)i*HIDDIM*HIDDIM,
        d_ob+i*HIDDIM, h, nullptr, h, ROWS_D, HIDDIM, HIDDIM, 0);
    k_ln<<<ROWS_D,256,0,stream>>>(h, d_ln2_g+i*HIDDIM, d_ln2_b+i*HIDDIM, lnb, HIDDIM);
    k_gemm128<<<dim3(8,160),256,0,stream>>>(lnb, d_ff1_w+(size_t)i*HIDDIM*4*HIDDIM,
        d_ff1_b+i*4*HIDDIM, nullptr, nullptr, big, ROWS_D, HIDDIM, 4*HIDDIM, 1);
    k_gemm128<<<dim3(2,160),256,0,stream>>>(big, d_ff2_w+(size_t)i*4*HIDDIM*HIDDIM,
        d_ff2_b+i*HIDDIM, h, nullptr, h, ROWS_D, 4*HIDDIM, HIDDIM, 0);
  }

  // ===== heads =====
  k_hout<<<10240,256,0,stream>>>(h, real, rep);
  k_ln<<<ROWS_E,256,0,stream>>>(rep, oc_ln_g, oc_ln_b, lnb, HIDDIM);
  k_gemm_small<<<120,256,0,stream>>>(lnb, oc_w, nullptr, out, ROWS_E, HIDDIM, 3, 0);
  k_gemm128<<<dim3(2,80),256,0,stream>>>(rep, oa1_w, oa1_b, nullptr, nullptr,
      big, ROWS_E, HIDDIM, HIDDIM, 1);
  k_gemm_small<<<640,256,0,stream>>>(big, oa2_w, oa2_b, out + 30720,
      ROWS_E, HIDDIM, 16, 0);
}